// Round 1
// baseline (131.134 us; speedup 1.0000x reference)
//
#include <hip/hip_runtime.h>

#define IMG 256
#define NPTS 320
#define NCHUNK 8
#define CHUNK (NPTS / NCHUNK)   // 40
#define PIX_PER_BLOCK 64
#define D0 2.0f
#define DSTEP (4.0f / 319.0f)
#define HALFV (765.0f / 512.0f)  // (3/256)*255*0.5
#define DENSITY_C 0.1f

// ---------------------------------------------------------------------------
// Kernel 1: ray-march. Block = 512 threads = 8 waves. lane (0..63) = pixel
// within block, wave (0..7) = depth chunk. Segmented front-to-back
// compositing combined via LDS; wave 0 writes raw rgb + per-block stats.
// ---------------------------------------------------------------------------
__global__ void render_kernel(const float* __restrict__ vol,
                              const float* __restrict__ R,
                              const float* __restrict__ T,
                              float* __restrict__ raw,
                              float* __restrict__ bsum,
                              float* __restrict__ bsumsq,
                              float* __restrict__ bmin,
                              float* __restrict__ bmax) {
  const int lane  = threadIdx.x & 63;
  const int chunk = threadIdx.x >> 6;
  const int pixel = blockIdx.x * PIX_PER_BLOCK + lane;
  const int h = pixel >> 8;
  const int w = pixel & 255;

  // camera-plane coords / FOCAL(=2)
  const float xh = (w * (2.0f / 255.0f) - 1.0f) * 0.5f;
  const float yh = (h * (2.0f / 255.0f) - 1.0f) * 0.5f;

  const float R00 = R[0], R01 = R[1], R02 = R[2];
  const float R10 = R[3], R11 = R[4], R12 = R[5];
  const float R20 = R[6], R21 = R[7], R22 = R[8];
  const float T0 = T[0], T1 = T[1], T2 = T[2];

  // pw = R * (pcam - T); pcam = (xh*d, yh*d, d)  -> pw is LINEAR in d.
  const float S = 127.5f / HALFV;  // voxel-index scale
  const float Cx = R00 * xh + R01 * yh + R02;
  const float Cy = R10 * xh + R11 * yh + R12;
  const float Cz = R20 * xh + R21 * yh + R22;
  const float Kx = -(R00 * T0 + R01 * T1 + R02 * T2);
  const float Ky = -(R10 * T0 + R11 * T1 + R12 * T2);
  const float Kz = -(R20 * T0 + R21 * T1 + R22 * T2);
  // ix(d) = (pwx/HALF + 1)*127.5 = (Cx*d + Kx)*S + 127.5
  const float ax = Cx * S, bx = Kx * S + 127.5f;
  const float ay = Cy * S, by = Ky * S + 127.5f;
  const float az = Cz * S, bz = Kz * S + 127.5f;
  // ix(p) = ix0 + p*dix  with d = D0 + p*DSTEP
  const float ix0 = ax * D0 + bx, dix = ax * DSTEP;
  const float iy0 = ay * D0 + by, diy = ay * DSTEP;
  const float iz0 = az * D0 + bz, diz = az * DSTEP;

  float acc = 0.0f;   // chunk-local composited rgb
  float Tac = 1.0f;   // chunk-local transmittance
  const int p0 = chunk * CHUNK;

  for (int i = 0; i < CHUNK; ++i) {
    const float pf = (float)(p0 + i);
    const float ix = fmaf(pf, dix, ix0);
    const float iy = fmaf(pf, diy, iy0);
    const float iz = fmaf(pf, diz, iz0);
    if (ix > -1.0f && ix < 256.0f && iy > -1.0f && iy < 256.0f &&
        iz > -1.0f && iz < 256.0f) {
      const float xf = floorf(ix), yf = floorf(iy), zf = floorf(iz);
      const float fx = ix - xf, fy = iy - yf, fz = iz - zf;
      const int x0 = (int)xf, y0 = (int)yf, z0 = (int)zf;
      // per-axis masked weights (validity factorizes across axes)
      const float wx0 = (x0 >= 0)   ? 1.0f - fx : 0.0f;
      const float wx1 = (x0 <= 254) ? fx        : 0.0f;
      const float wy0 = (y0 >= 0)   ? 1.0f - fy : 0.0f;
      const float wy1 = (y0 <= 254) ? fy        : 0.0f;
      const float wz0 = (z0 >= 0)   ? 1.0f - fz : 0.0f;
      const float wz1 = (z0 <= 254) ? fz        : 0.0f;
      const int xc0 = max(x0, 0),     xc1 = min(x0 + 1, 255);
      const int yc0 = max(y0, 0),     yc1 = min(y0 + 1, 255);
      const int zc0 = max(z0, 0),     zc1 = min(z0 + 1, 255);
      const int b00 = (zc0 * 256 + yc0) * 256;
      const int b01 = (zc0 * 256 + yc1) * 256;
      const int b10 = (zc1 * 256 + yc0) * 256;
      const int b11 = (zc1 * 256 + yc1) * 256;
      const float v000 = vol[b00 + xc0], v001 = vol[b00 + xc1];
      const float v010 = vol[b01 + xc0], v011 = vol[b01 + xc1];
      const float v100 = vol[b10 + xc0], v101 = vol[b10 + xc1];
      const float v110 = vol[b11 + xc0], v111 = vol[b11 + xc1];
      const float fs =
          wz0 * (wy0 * (wx0 * v000 + wx1 * v001) +
                 wy1 * (wx0 * v010 + wx1 * v011)) +
          wz1 * (wy0 * (wx0 * v100 + wx1 * v101) +
                 wy1 * (wx0 * v110 + wx1 * v111));
      const float wsum  = (wx0 + wx1) * (wy0 + wy1) * (wz0 + wz1);
      const float sigma = DENSITY_C * wsum;
      acc = fmaf(sigma * Tac, fs, acc);
      Tac *= (1.0f + 1e-10f - sigma);
    } else {
      Tac *= (1.0f + 1e-10f);  // sigma == 0 outside
    }
  }

  __shared__ float lrgb[NCHUNK][PIX_PER_BLOCK];
  __shared__ float lT[NCHUNK][PIX_PER_BLOCK];
  lrgb[chunk][lane] = acc;
  lT[chunk][lane]   = Tac;
  __syncthreads();

  if (threadIdx.x < 64) {
    float a = 0.0f, Tp = 1.0f;
#pragma unroll
    for (int c = 0; c < NCHUNK; ++c) {
      a  = fmaf(Tp, lrgb[c][lane], a);
      Tp *= lT[c][lane];
    }
    raw[pixel] = a;

    // wave-level stats reduction (64 lanes)
    float s = a, q = a * a, mn = a, mx = a;
#pragma unroll
    for (int off = 32; off > 0; off >>= 1) {
      s += __shfl_down(s, off, 64);
      q += __shfl_down(q, off, 64);
      mn = fminf(mn, __shfl_down(mn, off, 64));
      mx = fmaxf(mx, __shfl_down(mx, off, 64));
    }
    if (lane == 0) {
      bsum[blockIdx.x]   = s;
      bsumsq[blockIdx.x] = q;
      bmin[blockIdx.x]   = mn;
      bmax[blockIdx.x]   = mx;
    }
  }
}

// ---------------------------------------------------------------------------
// Kernel 2: reduce 1024 block partials -> normalization stats.
// ---------------------------------------------------------------------------
__global__ void stats_kernel(const float* __restrict__ bsum,
                             const float* __restrict__ bsumsq,
                             const float* __restrict__ bmin,
                             const float* __restrict__ bmax,
                             float* __restrict__ stats) {
  __shared__ double sS[256], sQ[256];
  __shared__ float sMn[256], sMx[256];
  const int t = threadIdx.x;
  double s = 0.0, q = 0.0;
  float mn = 3.4e38f, mx = -3.4e38f;
  for (int i = t; i < 1024; i += 256) {
    s += (double)bsum[i];
    q += (double)bsumsq[i];
    mn = fminf(mn, bmin[i]);
    mx = fmaxf(mx, bmax[i]);
  }
  sS[t] = s; sQ[t] = q; sMn[t] = mn; sMx[t] = mx;
  __syncthreads();
  for (int off = 128; off > 0; off >>= 1) {
    if (t < off) {
      sS[t] += sS[t + off];
      sQ[t] += sQ[t + off];
      sMn[t] = fminf(sMn[t], sMn[t + off]);
      sMx[t] = fmaxf(sMx[t], sMx[t + off]);
    }
    __syncthreads();
  }
  if (t == 0) {
    const double N = 65536.0;
    const double mean = sS[0] / N;
    double var = (sQ[0] - sS[0] * sS[0] / N) / (N - 1.0);
    if (var < 0.0) var = 0.0;
    const float stdeps = (float)sqrt(var) + 1e-8f;
    const float fmean = (float)mean;
    const float smin = (sMn[0] - fmean) / stdeps;
    const float smax = (sMx[0] - fmean) / stdeps;
    stats[0] = fmean;
    stats[1] = 1.0f / stdeps;
    stats[2] = smin;
    stats[3] = 1.0f / (smax - smin + 1e-8f);
  }
}

// ---------------------------------------------------------------------------
// Kernel 3: normalize + transpose (out[w][h] = f(raw[h][w])).
// ---------------------------------------------------------------------------
__global__ void finalize_kernel(const float* __restrict__ raw,
                                const float* __restrict__ stats,
                                float* __restrict__ out) {
  const int o = blockIdx.x * blockDim.x + threadIdx.x;
  const int wq = o >> 8;    // output row  (W index)
  const int hq = o & 255;   // output col  (H index)
  const float mean = stats[0], inv_std = stats[1];
  const float smin = stats[2], inv_range = stats[3];
  const float s = (raw[hq * 256 + wq] - mean) * inv_std;
  out[o] = (s - smin + 1e-8f) * inv_range;
}

extern "C" void kernel_launch(void* const* d_in, const int* in_sizes, int n_in,
                              void* d_out, int out_size, void* d_ws, size_t ws_size,
                              hipStream_t stream) {
  const float* vol = (const float*)d_in[0];  // (256,256,256) fp32
  const float* R   = (const float*)d_in[1];  // (1,3,3)
  const float* T   = (const float*)d_in[2];  // (1,3)
  float* out = (float*)d_out;                // 65536 fp32

  float* raw    = (float*)d_ws;              // 65536
  float* bsum   = raw + 65536;               // 1024
  float* bsumsq = bsum + 1024;               // 1024
  float* bmin   = bsumsq + 1024;             // 1024
  float* bmax   = bmin + 1024;               // 1024
  float* stats  = bmax + 1024;               // 4

  render_kernel<<<1024, 512, 0, stream>>>(vol, R, T, raw, bsum, bsumsq, bmin, bmax);
  stats_kernel<<<1, 256, 0, stream>>>(bsum, bsumsq, bmin, bmax, stats);
  finalize_kernel<<<256, 256, 0, stream>>>(raw, stats, out);
}

// Round 2
// 125.642 us; speedup vs baseline: 1.0437x; 1.0437x over previous
//
#include <hip/hip_runtime.h>

#define NPTS 320
#define NCHUNK 8
#define CHUNK (NPTS / NCHUNK)   // 40
#define PIX_PER_BLOCK 64
#define D0 2.0f
#define DSTEP (4.0f / 319.0f)
#define HALFV (765.0f / 512.0f)  // (3/256)*255*0.5
#define DENSITY_C 0.1f

// ---------------------------------------------------------------------------
// Kernel 1: ray-march. Block = 512 threads = 8 waves. lane (0..63) = pixel
// within block, wave (0..7) = depth chunk. Per-ray slab intervals split the
// chunk into [masked | fast-interior | masked] loops; fast path has no
// clamps/masks and sigma == 0.1 exactly. Segmented compositing via LDS.
// ---------------------------------------------------------------------------
__global__ __launch_bounds__(512, 8)
void render_kernel(const float* __restrict__ vol,
                   const float* __restrict__ R,
                   const float* __restrict__ T,
                   float* __restrict__ raw,
                   float* __restrict__ bsum,
                   float* __restrict__ bsumsq,
                   float* __restrict__ bmin,
                   float* __restrict__ bmax) {
  const int lane  = threadIdx.x & 63;
  const int chunk = threadIdx.x >> 6;
  const int pixel = blockIdx.x * PIX_PER_BLOCK + lane;
  const int h = pixel >> 8;
  const int w = pixel & 255;

  // camera-plane coords / FOCAL(=2)
  const float xh = (w * (2.0f / 255.0f) - 1.0f) * 0.5f;
  const float yh = (h * (2.0f / 255.0f) - 1.0f) * 0.5f;

  const float R00 = R[0], R01 = R[1], R02 = R[2];
  const float R10 = R[3], R11 = R[4], R12 = R[5];
  const float R20 = R[6], R21 = R[7], R22 = R[8];
  const float T0 = T[0], T1 = T[1], T2 = T[2];

  // pw = R * (pcam - T); pcam = (xh*d, yh*d, d) -> voxel coords LINEAR in d.
  const float S = 127.5f / HALFV;
  const float Cx = R00 * xh + R01 * yh + R02;
  const float Cy = R10 * xh + R11 * yh + R12;
  const float Cz = R20 * xh + R21 * yh + R22;
  const float Kx = -(R00 * T0 + R01 * T1 + R02 * T2);
  const float Ky = -(R10 * T0 + R11 * T1 + R12 * T2);
  const float Kz = -(R20 * T0 + R21 * T1 + R22 * T2);
  const float ax = Cx * S, bx = Kx * S + 127.5f;
  const float ay = Cy * S, by = Ky * S + 127.5f;
  const float az = Cz * S, bz = Kz * S + 127.5f;
  // ix(p) = ix0 + p*dix with d = D0 + p*DSTEP
  const float ix0 = ax * D0 + bx, dix = ax * DSTEP;
  const float iy0 = ay * D0 + by, diy = ay * DSTEP;
  const float iz0 = az * D0 + bz, diz = az * DSTEP;

  // --- slab intervals in p-space -------------------------------------------
  // fast interior: coord in [0.01, 254.99] on all axes (margins guard float
  //   error in the bound math; borderline samples fall to the exact masked
  //   path). outer: coord in (-1.01, 256.01) on all axes (outward margin so
  //   we never drop a contributing sample; masked path is safe for any p).
  float plo_in = -1e9f, phi_in = 1e9f, plo_out = -1e9f, phi_out = 1e9f;
  auto slab = [](float a, float b, float L, float H, float& lo, float& hi) {
    if (fabsf(a) < 1e-5f) {           // drift over 320 steps < 0.0032 < margin
      if (b < L || b > H) { lo = 1e9f; hi = -1e9f; }
    } else {
      const float p1 = (L - b) / a, p2 = (H - b) / a;
      lo = fmaxf(lo, fminf(p1, p2));
      hi = fminf(hi, fmaxf(p1, p2));
    }
  };
  slab(dix, ix0, 0.01f, 254.99f, plo_in, phi_in);
  slab(diy, iy0, 0.01f, 254.99f, plo_in, phi_in);
  slab(diz, iz0, 0.01f, 254.99f, plo_in, phi_in);
  slab(dix, ix0, -1.01f, 256.01f, plo_out, phi_out);
  slab(diy, iy0, -1.01f, 256.01f, plo_out, phi_out);
  slab(diz, iz0, -1.01f, 256.01f, plo_out, phi_out);

  const int i_in_lo  = (int)ceilf(fminf(fmaxf(plo_in, 0.0f), 320.0f));
  const int i_in_hi  = (int)floorf(fminf(fmaxf(phi_in, -1.0f), 319.0f)) + 1;
  const int i_out_lo = (int)ceilf(fminf(fmaxf(plo_out, 0.0f), 320.0f));
  const int i_out_hi = (int)floorf(fminf(fmaxf(phi_out, -1.0f), 319.0f)) + 1;

  float acc = 0.0f;   // chunk-local composited rgb
  float Tac = 1.0f;   // chunk-local transmittance
  const int p0 = chunk * CHUNK;

  // exact (clamped + masked) sample — identical math to the round-1 kernel
  auto masked_sample = [&](int p) {
    const float pf = (float)p;
    const float ix = fmaf(pf, dix, ix0);
    const float iy = fmaf(pf, diy, iy0);
    const float iz = fmaf(pf, diz, iz0);
    if (ix > -1.0f && ix < 256.0f && iy > -1.0f && iy < 256.0f &&
        iz > -1.0f && iz < 256.0f) {
      const float xf = floorf(ix), yf = floorf(iy), zf = floorf(iz);
      const float fx = ix - xf, fy = iy - yf, fz = iz - zf;
      const int x0 = (int)xf, y0 = (int)yf, z0 = (int)zf;
      const float wx0 = (x0 >= 0)   ? 1.0f - fx : 0.0f;
      const float wx1 = (x0 <= 254) ? fx        : 0.0f;
      const float wy0 = (y0 >= 0)   ? 1.0f - fy : 0.0f;
      const float wy1 = (y0 <= 254) ? fy        : 0.0f;
      const float wz0 = (z0 >= 0)   ? 1.0f - fz : 0.0f;
      const float wz1 = (z0 <= 254) ? fz        : 0.0f;
      const int xc0 = max(x0, 0),     xc1 = min(x0 + 1, 255);
      const int yc0 = max(y0, 0),     yc1 = min(y0 + 1, 255);
      const int zc0 = max(z0, 0),     zc1 = min(z0 + 1, 255);
      const int b00 = (zc0 * 256 + yc0) * 256;
      const int b01 = (zc0 * 256 + yc1) * 256;
      const int b10 = (zc1 * 256 + yc0) * 256;
      const int b11 = (zc1 * 256 + yc1) * 256;
      const float v000 = vol[b00 + xc0], v001 = vol[b00 + xc1];
      const float v010 = vol[b01 + xc0], v011 = vol[b01 + xc1];
      const float v100 = vol[b10 + xc0], v101 = vol[b10 + xc1];
      const float v110 = vol[b11 + xc0], v111 = vol[b11 + xc1];
      const float fs =
          wz0 * (wy0 * (wx0 * v000 + wx1 * v001) +
                 wy1 * (wx0 * v010 + wx1 * v011)) +
          wz1 * (wy0 * (wx0 * v100 + wx1 * v101) +
                 wy1 * (wx0 * v110 + wx1 * v111));
      const float wsum  = (wx0 + wx1) * (wy0 + wy1) * (wz0 + wz1);
      const float sigma = DENSITY_C * wsum;
      acc = fmaf(sigma * Tac, fs, acc);
      Tac *= (1.0f + 1e-10f - sigma);
    } else {
      Tac *= (1.0f + 1e-10f);
    }
  };

  // partition [lo_o, hi_o) into masked | fast | masked
  const int lo_o = max(p0, i_out_lo);
  const int hi_o = min(p0 + CHUNK, i_out_hi);
  const int lo_f = min(max(lo_o, i_in_lo), hi_o);
  const int hi_f = min(max(lo_f, i_in_hi), hi_o);

  for (int p = lo_o; p < lo_f; ++p) masked_sample(p);

#pragma unroll 4
  for (int p = lo_f; p < hi_f; ++p) {
    const float pf = (float)p;
    const float ix = fmaf(pf, dix, ix0);
    const float iy = fmaf(pf, diy, iy0);
    const float iz = fmaf(pf, diz, iz0);
    const int x0 = (int)ix, y0 = (int)iy, z0 = (int)iz;  // >=0: trunc==floor
    const float fx = ix - (float)x0;
    const float fy = iy - (float)y0;
    const float fz = iz - (float)z0;
    const int base = (z0 << 16) + (y0 << 8) + x0;
    const float v000 = vol[base],         v001 = vol[base + 1];
    const float v010 = vol[base + 256],   v011 = vol[base + 257];
    const float v100 = vol[base + 65536], v101 = vol[base + 65537];
    const float v110 = vol[base + 65792], v111 = vol[base + 65793];
    const float c00 = fmaf(fx, v001 - v000, v000);
    const float c01 = fmaf(fx, v011 - v010, v010);
    const float c10 = fmaf(fx, v101 - v100, v100);
    const float c11 = fmaf(fx, v111 - v110, v110);
    const float c0  = fmaf(fy, c01 - c00, c00);
    const float c1  = fmaf(fy, c11 - c10, c10);
    const float fs  = fmaf(fz, c1 - c0, c0);
    acc = fmaf(Tac * DENSITY_C, fs, acc);   // sigma == 0.1 exactly (wsum = 1)
    Tac *= (1.0f - DENSITY_C);              // fp32(0.9+1e-10) == fp32(0.9)
  }

  for (int p = hi_f; p < hi_o; ++p) masked_sample(p);

  __shared__ float lrgb[NCHUNK][PIX_PER_BLOCK];
  __shared__ float lT[NCHUNK][PIX_PER_BLOCK];
  lrgb[chunk][lane] = acc;
  lT[chunk][lane]   = Tac;
  __syncthreads();

  if (threadIdx.x < 64) {
    float a = 0.0f, Tp = 1.0f;
#pragma unroll
    for (int c = 0; c < NCHUNK; ++c) {
      a  = fmaf(Tp, lrgb[c][lane], a);
      Tp *= lT[c][lane];
    }
    raw[pixel] = a;

    float s = a, q = a * a, mn = a, mx = a;
#pragma unroll
    for (int off = 32; off > 0; off >>= 1) {
      s += __shfl_down(s, off, 64);
      q += __shfl_down(q, off, 64);
      mn = fminf(mn, __shfl_down(mn, off, 64));
      mx = fmaxf(mx, __shfl_down(mx, off, 64));
    }
    if (lane == 0) {
      bsum[blockIdx.x]   = s;
      bsumsq[blockIdx.x] = q;
      bmin[blockIdx.x]   = mn;
      bmax[blockIdx.x]   = mx;
    }
  }
}

// ---------------------------------------------------------------------------
// Kernel 2: fused stats + normalize + transpose. Each of 64 blocks (1024 thr)
// redundantly reduces the 1024 block-partials (L2-hot, ~16 KB) — kills the
// separate 1-block stats kernel and its launch — then normalizes 1024 pixels.
// ---------------------------------------------------------------------------
__global__ __launch_bounds__(1024)
void finalize_kernel(const float* __restrict__ raw,
                     const float* __restrict__ bsum,
                     const float* __restrict__ bsumsq,
                     const float* __restrict__ bmin,
                     const float* __restrict__ bmax,
                     float* __restrict__ out) {
  __shared__ double sS[1024];
  __shared__ double sQ[1024];
  __shared__ float sMn[1024], sMx[1024];
  const int t = threadIdx.x;
  sS[t] = (double)bsum[t];
  sQ[t] = (double)bsumsq[t];
  sMn[t] = bmin[t];
  sMx[t] = bmax[t];
  __syncthreads();
  for (int off = 512; off > 0; off >>= 1) {
    if (t < off) {
      sS[t] += sS[t + off];
      sQ[t] += sQ[t + off];
      sMn[t] = fminf(sMn[t], sMn[t + off]);
      sMx[t] = fmaxf(sMx[t], sMx[t + off]);
    }
    __syncthreads();
  }
  const double N = 65536.0;
  const double sum = sS[0], sumsq = sQ[0];
  const double mean = sum / N;
  double var = (sumsq - sum * sum / N) / (N - 1.0);
  if (var < 0.0) var = 0.0;
  const float stdeps = (float)sqrt(var) + 1e-8f;
  const float inv_std = 1.0f / stdeps;
  const float fmean = (float)mean;
  const float smin = (sMn[0] - fmean) * inv_std;
  const float smax = (sMx[0] - fmean) * inv_std;
  const float inv_range = 1.0f / (smax - smin + 1e-8f);

  const int o = blockIdx.x * 1024 + t;
  const int wq = o >> 8;    // output row (W index)
  const int hq = o & 255;   // output col (H index)
  const float s = (raw[hq * 256 + wq] - fmean) * inv_std;
  out[o] = (s - smin + 1e-8f) * inv_range;
}

extern "C" void kernel_launch(void* const* d_in, const int* in_sizes, int n_in,
                              void* d_out, int out_size, void* d_ws, size_t ws_size,
                              hipStream_t stream) {
  const float* vol = (const float*)d_in[0];  // (256,256,256) fp32
  const float* R   = (const float*)d_in[1];  // (1,3,3)
  const float* T   = (const float*)d_in[2];  // (1,3)
  float* out = (float*)d_out;                // 65536 fp32

  float* raw    = (float*)d_ws;              // 65536
  float* bsum   = raw + 65536;               // 1024
  float* bsumsq = bsum + 1024;               // 1024
  float* bmin   = bsumsq + 1024;             // 1024
  float* bmax   = bmin + 1024;               // 1024

  render_kernel<<<1024, 512, 0, stream>>>(vol, R, T, raw, bsum, bsumsq, bmin, bmax);
  finalize_kernel<<<64, 1024, 0, stream>>>(raw, bsum, bsumsq, bmin, bmax, out);
}

// Round 3
// 120.750 us; speedup vs baseline: 1.0860x; 1.0405x over previous
//
#include <hip/hip_runtime.h>

#define NPTS 320
#define NCHUNK 8
#define CHUNK (NPTS / NCHUNK)   // 40
#define PIX_PER_BLOCK 64
#define D0 2.0f
#define DSTEP (4.0f / 319.0f)
#define HALFV (765.0f / 512.0f)  // (3/256)*255*0.5
#define DENSITY_C 0.1f

// ---------------------------------------------------------------------------
// Kernel 1: ray-march. Block = 512 threads = 8 waves. lane (0..63) = pixel
// within block, wave (0..7) = depth chunk. Per-ray slab intervals split the
// chunk into [masked | fast-interior | masked] loops. Fast path processes
// GROUPS OF 4 samples with the compositing recurrence regrouped
// (t == 0.9 const in interior) so all 32 loads + 4 lerp trees per group are
// independent -> deep MLP. Segmented compositing combined via LDS.
// ---------------------------------------------------------------------------
__global__ __launch_bounds__(512, 6)
void render_kernel(const float* __restrict__ vol,
                   const float* __restrict__ R,
                   const float* __restrict__ T,
                   float* __restrict__ raw,
                   float* __restrict__ bsum,
                   float* __restrict__ bsumsq,
                   float* __restrict__ bmin,
                   float* __restrict__ bmax) {
  const int lane  = threadIdx.x & 63;
  const int chunk = threadIdx.x >> 6;
  const int pixel = blockIdx.x * PIX_PER_BLOCK + lane;
  const int h = pixel >> 8;
  const int w = pixel & 255;

  // camera-plane coords / FOCAL(=2)
  const float xh = (w * (2.0f / 255.0f) - 1.0f) * 0.5f;
  const float yh = (h * (2.0f / 255.0f) - 1.0f) * 0.5f;

  const float R00 = R[0], R01 = R[1], R02 = R[2];
  const float R10 = R[3], R11 = R[4], R12 = R[5];
  const float R20 = R[6], R21 = R[7], R22 = R[8];
  const float T0 = T[0], T1 = T[1], T2 = T[2];

  // pw = R * (pcam - T); pcam = (xh*d, yh*d, d) -> voxel coords LINEAR in d.
  const float S = 127.5f / HALFV;
  const float Cx = R00 * xh + R01 * yh + R02;
  const float Cy = R10 * xh + R11 * yh + R12;
  const float Cz = R20 * xh + R21 * yh + R22;
  const float Kx = -(R00 * T0 + R01 * T1 + R02 * T2);
  const float Ky = -(R10 * T0 + R11 * T1 + R12 * T2);
  const float Kz = -(R20 * T0 + R21 * T1 + R22 * T2);
  const float ax = Cx * S, bx = Kx * S + 127.5f;
  const float ay = Cy * S, by = Ky * S + 127.5f;
  const float az = Cz * S, bz = Kz * S + 127.5f;
  // ix(p) = ix0 + p*dix with d = D0 + p*DSTEP
  const float ix0 = ax * D0 + bx, dix = ax * DSTEP;
  const float iy0 = ay * D0 + by, diy = ay * DSTEP;
  const float iz0 = az * D0 + bz, diz = az * DSTEP;

  // --- slab intervals in p-space -------------------------------------------
  float plo_in = -1e9f, phi_in = 1e9f, plo_out = -1e9f, phi_out = 1e9f;
  auto slab = [](float a, float b, float L, float H, float& lo, float& hi) {
    if (fabsf(a) < 1e-5f) {           // drift over 320 steps < 0.0032 < margin
      if (b < L || b > H) { lo = 1e9f; hi = -1e9f; }
    } else {
      const float p1 = (L - b) / a, p2 = (H - b) / a;
      lo = fmaxf(lo, fminf(p1, p2));
      hi = fminf(hi, fmaxf(p1, p2));
    }
  };
  slab(dix, ix0, 0.01f, 254.99f, plo_in, phi_in);
  slab(diy, iy0, 0.01f, 254.99f, plo_in, phi_in);
  slab(diz, iz0, 0.01f, 254.99f, plo_in, phi_in);
  slab(dix, ix0, -1.01f, 256.01f, plo_out, phi_out);
  slab(diy, iy0, -1.01f, 256.01f, plo_out, phi_out);
  slab(diz, iz0, -1.01f, 256.01f, plo_out, phi_out);

  const int i_in_lo  = (int)ceilf(fminf(fmaxf(plo_in, 0.0f), 320.0f));
  const int i_in_hi  = (int)floorf(fminf(fmaxf(phi_in, -1.0f), 319.0f)) + 1;
  const int i_out_lo = (int)ceilf(fminf(fmaxf(plo_out, 0.0f), 320.0f));
  const int i_out_hi = (int)floorf(fminf(fmaxf(phi_out, -1.0f), 319.0f)) + 1;

  float acc = 0.0f;   // chunk-local composited rgb
  float Tac = 1.0f;   // chunk-local transmittance
  const int p0 = chunk * CHUNK;

  // exact (clamped + masked) sample — identical math to the round-1 kernel
  auto masked_sample = [&](int p) {
    const float pf = (float)p;
    const float ix = fmaf(pf, dix, ix0);
    const float iy = fmaf(pf, diy, iy0);
    const float iz = fmaf(pf, diz, iz0);
    if (ix > -1.0f && ix < 256.0f && iy > -1.0f && iy < 256.0f &&
        iz > -1.0f && iz < 256.0f) {
      const float xf = floorf(ix), yf = floorf(iy), zf = floorf(iz);
      const float fx = ix - xf, fy = iy - yf, fz = iz - zf;
      const int x0 = (int)xf, y0 = (int)yf, z0 = (int)zf;
      const float wx0 = (x0 >= 0)   ? 1.0f - fx : 0.0f;
      const float wx1 = (x0 <= 254) ? fx        : 0.0f;
      const float wy0 = (y0 >= 0)   ? 1.0f - fy : 0.0f;
      const float wy1 = (y0 <= 254) ? fy        : 0.0f;
      const float wz0 = (z0 >= 0)   ? 1.0f - fz : 0.0f;
      const float wz1 = (z0 <= 254) ? fz        : 0.0f;
      const int xc0 = max(x0, 0),     xc1 = min(x0 + 1, 255);
      const int yc0 = max(y0, 0),     yc1 = min(y0 + 1, 255);
      const int zc0 = max(z0, 0),     zc1 = min(z0 + 1, 255);
      const int b00 = (zc0 * 256 + yc0) * 256;
      const int b01 = (zc0 * 256 + yc1) * 256;
      const int b10 = (zc1 * 256 + yc0) * 256;
      const int b11 = (zc1 * 256 + yc1) * 256;
      const float v000 = vol[b00 + xc0], v001 = vol[b00 + xc1];
      const float v010 = vol[b01 + xc0], v011 = vol[b01 + xc1];
      const float v100 = vol[b10 + xc0], v101 = vol[b10 + xc1];
      const float v110 = vol[b11 + xc0], v111 = vol[b11 + xc1];
      const float fs =
          wz0 * (wy0 * (wx0 * v000 + wx1 * v001) +
                 wy1 * (wx0 * v010 + wx1 * v011)) +
          wz1 * (wy0 * (wx0 * v100 + wx1 * v101) +
                 wy1 * (wx0 * v110 + wx1 * v111));
      const float wsum  = (wx0 + wx1) * (wy0 + wy1) * (wz0 + wz1);
      const float sigma = DENSITY_C * wsum;
      acc = fmaf(sigma * Tac, fs, acc);
      Tac *= (1.0f + 1e-10f - sigma);
    } else {
      Tac *= (1.0f + 1e-10f);
    }
  };

  // interior trilinear sample (no clamps/masks; x0,y0,z0 in [0,254])
  auto fast_sample = [&](int p) -> float {
    const float pf = (float)p;
    const float ix = fmaf(pf, dix, ix0);
    const float iy = fmaf(pf, diy, iy0);
    const float iz = fmaf(pf, diz, iz0);
    const int x0 = (int)ix, y0 = (int)iy, z0 = (int)iz;  // >=0: trunc==floor
    const float fx = ix - (float)x0;
    const float fy = iy - (float)y0;
    const float fz = iz - (float)z0;
    const int base = (z0 << 16) + (y0 << 8) + x0;
    const float v000 = vol[base],         v001 = vol[base + 1];
    const float v010 = vol[base + 256],   v011 = vol[base + 257];
    const float v100 = vol[base + 65536], v101 = vol[base + 65537];
    const float v110 = vol[base + 65792], v111 = vol[base + 65793];
    const float c00 = fmaf(fx, v001 - v000, v000);
    const float c01 = fmaf(fx, v011 - v010, v010);
    const float c10 = fmaf(fx, v101 - v100, v100);
    const float c11 = fmaf(fx, v111 - v110, v110);
    const float c0  = fmaf(fy, c01 - c00, c00);
    const float c1  = fmaf(fy, c11 - c10, c10);
    return fmaf(fz, c1 - c0, c0);
  };

  // partition [lo_o, hi_o) into masked | fast | masked
  const int lo_o = max(p0, i_out_lo);
  const int hi_o = min(p0 + CHUNK, i_out_hi);
  const int lo_f = min(max(lo_o, i_in_lo), hi_o);
  const int hi_f = min(max(lo_f, i_in_hi), hi_o);

  for (int p = lo_o; p < lo_f; ++p) masked_sample(p);

  // groups of 4: recurrence regrouped (sigma == 0.1, t == 0.9 in interior);
  // all 32 loads + 4 lerp trees per group are independent.
  int p = lo_f;
#pragma unroll 1
  for (; p + 4 <= hi_f; p += 4) {
    const float fs0 = fast_sample(p);
    const float fs1 = fast_sample(p + 1);
    const float fs2 = fast_sample(p + 2);
    const float fs3 = fast_sample(p + 3);
    const float g = fmaf(0.729f, fs3,
                    fmaf(0.81f,  fs2,
                    fmaf(0.9f,   fs1, fs0)));
    acc = fmaf(Tac * DENSITY_C, g, acc);
    Tac *= 0.6561f;   // 0.9^4
  }
  for (; p < hi_f; ++p) {
    const float fs = fast_sample(p);
    acc = fmaf(Tac * DENSITY_C, fs, acc);
    Tac *= (1.0f - DENSITY_C);
  }

  for (p = hi_f; p < hi_o; ++p) masked_sample(p);

  __shared__ float lrgb[NCHUNK][PIX_PER_BLOCK];
  __shared__ float lT[NCHUNK][PIX_PER_BLOCK];
  lrgb[chunk][lane] = acc;
  lT[chunk][lane]   = Tac;
  __syncthreads();

  if (threadIdx.x < 64) {
    float a = 0.0f, Tp = 1.0f;
#pragma unroll
    for (int c = 0; c < NCHUNK; ++c) {
      a  = fmaf(Tp, lrgb[c][lane], a);
      Tp *= lT[c][lane];
    }
    raw[pixel] = a;

    float s = a, q = a * a, mn = a, mx = a;
#pragma unroll
    for (int off = 32; off > 0; off >>= 1) {
      s += __shfl_down(s, off, 64);
      q += __shfl_down(q, off, 64);
      mn = fminf(mn, __shfl_down(mn, off, 64));
      mx = fmaxf(mx, __shfl_down(mx, off, 64));
    }
    if (lane == 0) {
      bsum[blockIdx.x]   = s;
      bsumsq[blockIdx.x] = q;
      bmin[blockIdx.x]   = mn;
      bmax[blockIdx.x]   = mx;
    }
  }
}

// ---------------------------------------------------------------------------
// Kernel 2: fused stats + normalize + transpose (unchanged from round 2).
// ---------------------------------------------------------------------------
__global__ __launch_bounds__(1024)
void finalize_kernel(const float* __restrict__ raw,
                     const float* __restrict__ bsum,
                     const float* __restrict__ bsumsq,
                     const float* __restrict__ bmin,
                     const float* __restrict__ bmax,
                     float* __restrict__ out) {
  __shared__ double sS[1024];
  __shared__ double sQ[1024];
  __shared__ float sMn[1024], sMx[1024];
  const int t = threadIdx.x;
  sS[t] = (double)bsum[t];
  sQ[t] = (double)bsumsq[t];
  sMn[t] = bmin[t];
  sMx[t] = bmax[t];
  __syncthreads();
  for (int off = 512; off > 0; off >>= 1) {
    if (t < off) {
      sS[t] += sS[t + off];
      sQ[t] += sQ[t + off];
      sMn[t] = fminf(sMn[t], sMn[t + off]);
      sMx[t] = fmaxf(sMx[t], sMx[t + off]);
    }
    __syncthreads();
  }
  const double N = 65536.0;
  const double sum = sS[0], sumsq = sQ[0];
  const double mean = sum / N;
  double var = (sumsq - sum * sum / N) / (N - 1.0);
  if (var < 0.0) var = 0.0;
  const float stdeps = (float)sqrt(var) + 1e-8f;
  const float inv_std = 1.0f / stdeps;
  const float fmean = (float)mean;
  const float smin = (sMn[0] - fmean) * inv_std;
  const float smax = (sMx[0] - fmean) * inv_std;
  const float inv_range = 1.0f / (smax - smin + 1e-8f);

  const int o = blockIdx.x * 1024 + t;
  const int wq = o >> 8;    // output row (W index)
  const int hq = o & 255;   // output col (H index)
  const float s = (raw[hq * 256 + wq] - fmean) * inv_std;
  out[o] = (s - smin + 1e-8f) * inv_range;
}

extern "C" void kernel_launch(void* const* d_in, const int* in_sizes, int n_in,
                              void* d_out, int out_size, void* d_ws, size_t ws_size,
                              hipStream_t stream) {
  const float* vol = (const float*)d_in[0];  // (256,256,256) fp32
  const float* R   = (const float*)d_in[1];  // (1,3,3)
  const float* T   = (const float*)d_in[2];  // (1,3)
  float* out = (float*)d_out;                // 65536 fp32

  float* raw    = (float*)d_ws;              // 65536
  float* bsum   = raw + 65536;               // 1024
  float* bsumsq = bsum + 1024;               // 1024
  float* bmin   = bsumsq + 1024;             // 1024
  float* bmax   = bmin + 1024;               // 1024

  render_kernel<<<1024, 512, 0, stream>>>(vol, R, T, raw, bsum, bsumsq, bmin, bmax);
  finalize_kernel<<<64, 1024, 0, stream>>>(raw, bsum, bsumsq, bmin, bmax, out);
}